// Round 1
// baseline (501.954 us; speedup 1.0000x reference)
//
#include <hip/hip_runtime.h>
#include <cstdint>
#include <cstddef>

#define HW 25600

// ---------- helpers ----------

__device__ __forceinline__ float wred(float v) {
#pragma unroll
    for (int off = 32; off; off >>= 1) v += __shfl_down(v, off, 64);
    return v;
}

__device__ float blockReduce256(float v, float* s4) {
    v = wred(v);
    __syncthreads();
    if ((threadIdx.x & 63) == 0) s4[threadIdx.x >> 6] = v;
    __syncthreads();
    return s4[0] + s4[1] + s4[2] + s4[3];
}

__device__ double blockReduce256D(double v, double* s4) {
#pragma unroll
    for (int off = 32; off; off >>= 1) v += __shfl_down(v, off, 64);
    __syncthreads();
    if ((threadIdx.x & 63) == 0) s4[threadIdx.x >> 6] = v;
    __syncthreads();
    return s4[0] + s4[1] + s4[2] + s4[3];
}

// idx[q]: q = i*100+k -> g=q>>8, j=q&255 ; value = 160*(j>>4)+16*(j&15)+2560*(g>>4)+(g&15)
__device__ __forceinline__ int idxval(int q) {
    int g = q >> 8, j = q & 255;
    return ((j >> 4) * 160) + ((j & 15) * 16) + ((g >> 4) * 2560) + (g & 15);
}

// ---------- K1: softmax / gather / weights + cnt,E partials ----------
// grid 400 = (b,100 q-chunks), block 256. q_local = r*256+t -> g=r, j=t.

__global__ __launch_bounds__(256) void k1_prep(
    const float* __restrict__ PredS, const float* __restrict__ PredT,
    const int* __restrict__ target,
    int* __restrict__ cls_arr, float* __restrict__ wT_arr,
    float* __restrict__ w_arr, float* __restrict__ partial_prep)
{
    __shared__ float s4[4];
    int blk = blockIdx.x;
    int b = blk / 100, r = blk - b * 100;
    int t = threadIdx.x;
    int ql = r * 256 + t;
    int v = ((t >> 4) * 160) + ((t & 15) * 16) + ((r >> 4) * 2560) + (r & 15);

    int cls = target[b * HW + v];

    const float* pS = PredS + b * 4 * HW + v;
    float a0 = pS[0], a1 = pS[HW], a2 = pS[2 * HW], a3 = pS[3 * HW];
    float mS = fmaxf(fmaxf(a0, a1), fmaxf(a2, a3));
    float e0 = expf(a0 - mS), e1 = expf(a1 - mS), e2 = expf(a2 - mS), e3 = expf(a3 - mS);
    float invS = 1.0f / (e0 + e1 + e2 + e3);
    float wei_s = ((cls == 0) ? e0 : (cls == 1) ? e1 : (cls == 2) ? e2 : e3) * invS;

    const float* pT = PredT + b * 4 * HW + v;
    float c0 = pT[0], c1 = pT[HW], c2 = pT[2 * HW], c3 = pT[3 * HW];
    float mT = fmaxf(fmaxf(c0, c1), fmaxf(c2, c3));
    float f0 = expf(c0 - mT), f1 = expf(c1 - mT), f2 = expf(c2 - mT), f3 = expf(c3 - mT);
    float invT = 1.0f / (f0 + f1 + f2 + f3);
    float tn0 = f0 * invT, tn1 = f1 * invT, tn2 = f2 * invT, tn3 = f3 * invT;
    float wei_t = (cls == 0) ? tn0 : (cls == 1) ? tn1 : (cls == 2) ? tn2 : tn3;

    cls_arr[b * HW + ql] = cls;
    wT_arr[b * HW + ql] = wei_t;
    w_arr[b * HW + ql] = (1.0f - wei_s) * wei_t;

    int ob = blk * 20;
#define RED1(expr, slot) { float rv = blockReduce256((expr), s4); if (t == 0) partial_prep[ob + (slot)] = rv; }
    RED1((cls == 0) ? 1.f : 0.f, 0)
    RED1((cls == 1) ? 1.f : 0.f, 1)
    RED1((cls == 2) ? 1.f : 0.f, 2)
    RED1((cls == 3) ? 1.f : 0.f, 3)
    RED1((cls == 0) ? tn0 : 0.f, 4)
    RED1((cls == 0) ? tn1 : 0.f, 5)
    RED1((cls == 0) ? tn2 : 0.f, 6)
    RED1((cls == 0) ? tn3 : 0.f, 7)
    RED1((cls == 1) ? tn0 : 0.f, 8)
    RED1((cls == 1) ? tn1 : 0.f, 9)
    RED1((cls == 1) ? tn2 : 0.f, 10)
    RED1((cls == 1) ? tn3 : 0.f, 11)
    RED1((cls == 2) ? tn0 : 0.f, 12)
    RED1((cls == 2) ? tn1 : 0.f, 13)
    RED1((cls == 2) ? tn2 : 0.f, 14)
    RED1((cls == 2) ? tn3 : 0.f, 15)
    RED1((cls == 3) ? tn0 : 0.f, 16)
    RED1((cls == 3) ? tn1 : 0.f, 17)
    RED1((cls == 3) ? tn2 : 0.f, 18)
    RED1((cls == 3) ? tn3 : 0.f, 19)
#undef RED1
}

// ---------- K1.5: reduce prep partials -> cnt[b][4], E[b][16] ----------
__global__ void k15_red(const float* __restrict__ partial_prep,
                        float* __restrict__ cnt, float* __restrict__ E)
{
    int t = threadIdx.x;
    if (t < 80) {
        int b = t / 20, s = t - (t / 20) * 20;
        float a = 0.f;
        for (int r = 0; r < 100; ++r) a += partial_prep[(b * 100 + r) * 20 + s];
        if (s < 4) cnt[b * 4 + s] = a;
        else       E[b * 16 + (s - 4)] = a;
    }
}

// ---------- K2: W matrices. grid 1024 = (b,i), block 128 (k<100 active) ----------
__global__ __launch_bounds__(128) void k2_w(
    const float* __restrict__ Satt, const float* __restrict__ Tatt,
    const int* __restrict__ cls_arr, const float* __restrict__ wT_arr,
    float* __restrict__ W_S, float* __restrict__ W_T)
{
    __shared__ float Al[100 * 101];
    __shared__ int cls_s[100];
    __shared__ float wTs[100];
    int blk = blockIdx.x;
    int b = blk >> 8, i = blk & 255;
    int t = threadIdx.x;
    if (t < 100) {
        cls_s[t] = cls_arr[b * HW + i * 100 + t];
        wTs[t] = wT_arr[b * HW + i * 100 + t];
    }
    // S side (no weight)
    for (int f = t; f < 10000; f += 128) Al[f + f / 100] = Satt[b * 10000 + f];
    __syncthreads();
    if (t < 100) {
        float a0 = 0, a1 = 0, a2 = 0, a3 = 0;
        for (int jc = 0; jc < 100; ++jc) {
            float a = Al[t * 101 + jc];
            int cc = cls_s[jc];
            a0 += (cc == 0) ? a : 0.f;
            a1 += (cc == 1) ? a : 0.f;
            a2 += (cc == 2) ? a : 0.f;
            a3 += (cc == 3) ? a : 0.f;
        }
        int basew = b * 102400 + i * 100 + t;
        W_S[basew] = a0; W_S[basew + 25600] = a1; W_S[basew + 51200] = a2; W_S[basew + 76800] = a3;
    }
    __syncthreads();
    // T side (weighted by wei_t at each pixel)
    for (int f = t; f < 10000; f += 128) Al[f + f / 100] = Tatt[b * 10000 + f];
    __syncthreads();
    if (t < 100) {
        float a0 = 0, a1 = 0, a2 = 0, a3 = 0;
        for (int jc = 0; jc < 100; ++jc) {
            float a = Al[t * 101 + jc] * wTs[jc];
            int cc = cls_s[jc];
            a0 += (cc == 0) ? a : 0.f;
            a1 += (cc == 1) ? a : 0.f;
            a2 += (cc == 2) ? a : 0.f;
            a3 += (cc == 3) ? a : 0.f;
        }
        int basew = b * 102400 + i * 100 + t;
        W_T[basew] = a0; W_T[basew + 25600] = a1; W_T[basew + 51200] = a2; W_T[basew + 76800] = a3;
    }
}

// ---------- K3: SumTS/SumTT. grid 1024 = (b,c), block 256 ----------
__global__ __launch_bounds__(256) void k3_sums(
    const float* __restrict__ featS, const float* __restrict__ featT,
    const float* __restrict__ W_S, const float* __restrict__ W_T,
    float* __restrict__ SumTS, float* __restrict__ SumTT)
{
    __shared__ float redl[32];
    int blk = blockIdx.x;
    int b = blk >> 8, c = blk & 255;
    int t = threadIdx.x, w = t >> 6, lane = t & 63;
    int tp = ((t >> 4) * 160) + ((t & 15) * 16);
    const float* fS = featS + (b * 256 + c) * HW;
    const float* fT = featT + (b * 256 + c) * HW;
    float acc[8];
#pragma unroll
    for (int s = 0; s < 8; ++s) acc[s] = 0.f;
    for (int it = 0; it < 100; ++it) {
        int o = tp + ((it >> 4) * 2560) + (it & 15);
        int q = it * 256 + t;
        float vs = fS[o], vt = fT[o];
#pragma unroll
        for (int j = 0; j < 4; ++j) {
            acc[j]     += vs * W_S[(b * 4 + j) * HW + q];
            acc[4 + j] += vt * W_T[(b * 4 + j) * HW + q];
        }
    }
#pragma unroll
    for (int s = 0; s < 8; ++s) {
        float v = wred(acc[s]);
        if (lane == 0) redl[w * 8 + s] = v;
    }
    __syncthreads();
    if (t == 0) {
#pragma unroll
        for (int s = 0; s < 8; ++s) {
            float v = redl[s] + redl[8 + s] + redl[16 + s] + redl[24 + s];
            if (s < 4) SumTS[(b * 256 + c) * 4 + s] = v;
            else       SumTT[(b * 256 + c) * 4 + (s - 4)] = v;
        }
    }
}

// ---------- K4.5: per-batch tables (colnorms + denominators) ----------
__global__ void k45_tbl(const float* __restrict__ SumTS, const float* __restrict__ SumTT,
                        const float* __restrict__ cnt, const float* __restrict__ E,
                        float* __restrict__ tbl)
{
    int t = threadIdx.x;
    if (t < 32) {
        int b = t >> 3, sj = t & 7, stv = sj >> 2, j = sj & 3;
        const float* S = stv ? SumTT : SumTS;
        float s = 0.f;
        for (int c = 0; c < 256; ++c) {
            float x = S[(b * 256 + c) * 4 + j];
            s += x * x;
        }
        tbl[b * 32 + stv * 4 + j] = sqrtf(s);
    } else if (t < 48) {
        int q = t - 32;
        int b = q >> 2, i = q & 3;
        tbl[b * 32 + 8 + 0 * 4 + i] = cnt[b * 4 + i] + 1e-6f;
        tbl[b * 32 + 8 + 1 * 4 + i] = cnt[b * 4 + (i ^ 2)] + 1e-6f;
        tbl[b * 32 + 8 + 2 * 4 + i] = cnt[b * 4 + (i ^ 3)] + 1.0f;
        tbl[b * 32 + 20 + 0 * 4 + i] = E[b * 16 + i * 4 + (i ^ 1)] + 1e-6f;
        tbl[b * 32 + 20 + 1 * 4 + i] = E[b * 16 + 5 * (i ^ 2)] + 1e-6f;
        tbl[b * 32 + 20 + 2 * 4 + i] = E[b * 16 + 5 * (i ^ 3)] + 1.0f;
    }
}

// ---------- K4: main einsum + per-pixel n2/dot. grid 2048 = (st,b,i0) XCD-swizzled ----------
__global__ __launch_bounds__(256) void k4_main(
    const float* __restrict__ featS, const float* __restrict__ featT,
    const float* __restrict__ Satt, const float* __restrict__ Tatt,
    const float* __restrict__ SumTS, const float* __restrict__ SumTT,
    float* __restrict__ n2S, float* __restrict__ n2T,
    float* __restrict__ dotS, float* __restrict__ dotT)
{
    __shared__ float Al[10000];
    __shared__ __align__(16) float stage[3600];
    __shared__ __align__(16) float Sl[1024];
    __shared__ int o_l[100];

    int x = blockIdx.x;
    int xcd = x & 7, rr = x >> 3;
    int st = rr >> 7, b = (rr >> 5) & 3, i0 = (rr & 31) | (xcd << 5);
    int t = threadIdx.x, w = t >> 6, lane = t & 63;

    const float* feat = st ? featT : featS;
    const float* A    = st ? Tatt  : Satt;
    const float* Sum  = st ? SumTT : SumTS;

    for (int f = t; f < 10000; f += 256) Al[f] = A[b * 10000 + f];
    for (int f = t; f < 1024; f += 256) Sl[f] = Sum[b * 1024 + f];
    if (t < 100) o_l[t] = idxval(i0 * 100 + t);

    int jc1 = lane;
    int jc2 = lane + 64;
    int jc2c = jc2 < 100 ? jc2 : 99;
    float accA[5], accB[5];
#pragma unroll
    for (int s = 0; s < 5; ++s) { accA[s] = 0.f; accB[s] = 0.f; }
    const float* fpb = feat + (size_t)(b * 256) * HW;

    for (int ci = 0; ci < 8; ++ci) {
        __syncthreads();
        int c0 = ci * 32;
        for (int f = t; f < 3200; f += 256) {
            int cl = f / 100;
            int k = f - cl * 100;
            stage[k * 36 + cl] = fpb[(c0 + cl) * HW + o_l[k]];
        }
        __syncthreads();

        float ts[8], tu[8];
#pragma unroll
        for (int z = 0; z < 8; ++z) { ts[z] = 0.f; tu[z] = 0.f; }
        for (int k = 0; k < 100; ++k) {
            float4 fa = *(const float4*)(stage + k * 36 + w * 8);
            float4 fb = *(const float4*)(stage + k * 36 + w * 8 + 4);
            float a1 = Al[k * 100 + jc1];
            float a2 = Al[k * 100 + jc2c];
            float fv[8] = { fa.x, fa.y, fa.z, fa.w, fb.x, fb.y, fb.z, fb.w };
#pragma unroll
            for (int z = 0; z < 8; ++z) {
                ts[z] += fv[z] * a1;
                tu[z] += fv[z] * a2;
            }
        }
        int cb = c0 + w * 8;
#pragma unroll
        for (int z = 0; z < 8; ++z) {
            float4 sv = *(const float4*)(Sl + (cb + z) * 4);
            accA[0] += ts[z] * ts[z];
            accA[1] += ts[z] * sv.x; accA[2] += ts[z] * sv.y;
            accA[3] += ts[z] * sv.z; accA[4] += ts[z] * sv.w;
            accB[0] += tu[z] * tu[z];
            accB[1] += tu[z] * sv.x; accB[2] += tu[z] * sv.y;
            accB[3] += tu[z] * sv.z; accB[4] += tu[z] * sv.w;
        }
    }
    __syncthreads();
    float* red = stage;  // 2560 <= 3600
#pragma unroll
    for (int s = 0; s < 5; ++s) {
        red[t * 10 + s] = accA[s];
        red[t * 10 + 5 + s] = accB[s];
    }
    __syncthreads();
    if (t < 64) {
        float o[10];
#pragma unroll
        for (int s = 0; s < 10; ++s)
            o[s] = red[t * 10 + s] + red[(t + 64) * 10 + s] + red[(t + 128) * 10 + s] + red[(t + 192) * 10 + s];
        float* n2 = st ? n2T : n2S;
        float* dd = st ? dotT : dotS;
        int pq1 = b * HW + i0 * 100 + t;
        n2[pq1] = o[0];
        dd[pq1 * 4 + 0] = o[1]; dd[pq1 * 4 + 1] = o[2];
        dd[pq1 * 4 + 2] = o[3]; dd[pq1 * 4 + 3] = o[4];
        if (t < 36) {
            int pq2 = pq1 + 64;
            n2[pq2] = o[5];
            dd[pq2 * 4 + 0] = o[6]; dd[pq2 * 4 + 1] = o[7];
            dd[pq2 * 4 + 2] = o[8]; dd[pq2 * 4 + 3] = o[9];
        }
    }
}

// ---------- K5: cosines + squared diff; per-block double partials ----------
__global__ __launch_bounds__(256) void k5_final(
    const int* __restrict__ cls_arr, const float* __restrict__ w_arr,
    const float* __restrict__ n2S, const float* __restrict__ n2T,
    const float* __restrict__ dotS, const float* __restrict__ dotT,
    const float* __restrict__ tbl, double* __restrict__ partial_res)
{
    __shared__ double s4[4];
    int blk = blockIdx.x;
    int b = blk / 100, r = blk - b * 100;
    int t = threadIdx.x;
    int pq = b * HW + r * 256 + t;

    int i = cls_arr[pq];
    float wv = w_arr[pq];
    float sqS = sqrtf(n2S[pq]);
    float sqT = sqrtf(n2T[pq]);
    float4 dS = *(const float4*)(dotS + pq * 4);
    float4 dT = *(const float4*)(dotT + pq * 4);
    const float* tb = tbl + b * 32;

    double acc = 0.0;
#pragma unroll
    for (int v = 0; v < 3; ++v) {
        int j = i ^ (v + 1);
        float dsj = (j == 0) ? dS.x : (j == 1) ? dS.y : (j == 2) ? dS.z : dS.w;
        float dtj = (j == 0) ? dT.x : (j == 1) ? dT.y : (j == 2) ? dT.z : dT.w;
        float cnS = tb[j], cnT = tb[4 + j];
        float denS = tb[8 + v * 4 + i], denT = tb[20 + v * 4 + i];
        float cs = (dsj / denS) / fmaxf(sqS * (cnS / denS), 1e-8f);
        float ct = (dtj / denT) / fmaxf(sqT * (cnT / denT), 1e-8f);
        float vs = wv * cs, vt = wv * ct;
        float d = vs - vt;
        acc += (double)d * (double)d;
    }
    double tot = blockReduce256D(acc, s4);
    if (t == 0) partial_res[blk] = tot;
}

// ---------- K6: final deterministic sum ----------
__global__ void k6_out(const double* __restrict__ partial_res, float* __restrict__ out)
{
    if (threadIdx.x == 0 && blockIdx.x == 0) {
        double s = 0.0;
        for (int q = 0; q < 400; ++q) s += partial_res[q];
        out[0] = (float)(s / 307200.0);
    }
}

// ---------- launch ----------
extern "C" void kernel_launch(void* const* d_in, const int* in_sizes, int n_in,
                              void* d_out, int out_size, void* d_ws, size_t ws_size,
                              hipStream_t stream)
{
    const float* feat_S  = (const float*)d_in[0];
    const float* feat_T  = (const float*)d_in[1];
    const float* Pred_S  = (const float*)d_in[2];
    const float* Pred_T  = (const float*)d_in[3];
    const float* S_atten = (const float*)d_in[4];
    const float* T_atten = (const float*)d_in[5];
    const int*   target  = (const int*)d_in[6];

    float* ws = (float*)d_ws;
    float* W_S   = ws;                       // 409600
    float* W_T   = ws + 409600;              // 409600
    int*   cls_a = (int*)(ws + 819200);      // 102400
    float* wT_a  = ws + 921600;              // 102400
    float* w_a   = ws + 1024000;             // 102400
    float* SumTS = ws + 1126400;             // 4096
    float* SumTT = ws + 1130496;             // 4096
    float* n2S   = ws + 1134592;             // 102400
    float* n2T   = ws + 1236992;             // 102400
    float* dotS  = ws + 1339392;             // 409600
    float* dotT  = ws + 1748992;             // 409600
    float* pprep = ws + 2158592;             // 8000
    float* cnt   = ws + 2166592;             // 16
    float* E     = ws + 2166608;             // 64
    float* tbl   = ws + 2166672;             // 128
    double* pres = (double*)(ws + 2166800);  // 400 doubles (8-byte aligned offset)

    k1_prep<<<400, 256, 0, stream>>>(Pred_S, Pred_T, target, cls_a, wT_a, w_a, pprep);
    k15_red<<<1, 128, 0, stream>>>(pprep, cnt, E);
    k2_w<<<1024, 128, 0, stream>>>(S_atten, T_atten, cls_a, wT_a, W_S, W_T);
    k3_sums<<<1024, 256, 0, stream>>>(feat_S, feat_T, W_S, W_T, SumTS, SumTT);
    k45_tbl<<<1, 64, 0, stream>>>(SumTS, SumTT, cnt, E, tbl);
    k4_main<<<2048, 256, 0, stream>>>(feat_S, feat_T, S_atten, T_atten, SumTS, SumTT,
                                      n2S, n2T, dotS, dotT);
    k5_final<<<400, 256, 0, stream>>>(cls_a, w_a, n2S, n2T, dotS, dotT, tbl, pres);
    k6_out<<<1, 64, 0, stream>>>(pres, (float*)d_out);
}

// Round 2
// 184.658 us; speedup vs baseline: 2.7183x; 2.7183x over previous
//
#include <hip/hip_runtime.h>
#include <cstdint>
#include <cstddef>

#define HW 25600

typedef __attribute__((ext_vector_type(8))) short bf16x8;
typedef __attribute__((ext_vector_type(16))) float f32x16;

union ABu { bf16x8 v; uint2 u[2]; };

__device__ __forceinline__ f32x16 zero16() {
    f32x16 z;
#pragma unroll
    for (int i = 0; i < 16; ++i) z[i] = 0.f;
    return z;
}

__device__ __forceinline__ unsigned short f2bf(float x) {
    unsigned u = __builtin_bit_cast(unsigned, x);
    unsigned r = (u + 0x7FFF + ((u >> 16) & 1)) >> 16;
    return (unsigned short)r;
}

__device__ __forceinline__ float wred(float v) {
#pragma unroll
    for (int off = 32; off; off >>= 1) v += __shfl_down(v, off, 64);
    return v;
}

__device__ float blockReduce256(float v, float* s4) {
    v = wred(v);
    __syncthreads();
    if ((threadIdx.x & 63) == 0) s4[threadIdx.x >> 6] = v;
    __syncthreads();
    return s4[0] + s4[1] + s4[2] + s4[3];
}

__device__ double blockReduce256D(double v, double* s4) {
#pragma unroll
    for (int off = 32; off; off >>= 1) v += __shfl_down(v, off, 64);
    __syncthreads();
    if ((threadIdx.x & 63) == 0) s4[threadIdx.x >> 6] = v;
    __syncthreads();
    return s4[0] + s4[1] + s4[2] + s4[3];
}

// flat gather value for q = g*256 + j
__device__ __forceinline__ int idxval(int q) {
    int g = q >> 8, j = q & 255;
    return ((j >> 4) * 160) + ((j & 15) * 16) + ((g >> 4) * 2560) + (g & 15);
}

// ---------- K1: softmax / gather / weights + cnt,E partials (unchanged) ----------
__global__ __launch_bounds__(256) void k1_prep(
    const float* __restrict__ PredS, const float* __restrict__ PredT,
    const int* __restrict__ target,
    int* __restrict__ cls_arr, float* __restrict__ wT_arr,
    float* __restrict__ w_arr, float* __restrict__ partial_prep)
{
    __shared__ float s4[4];
    int blk = blockIdx.x;
    int b = blk / 100, r = blk - b * 100;
    int t = threadIdx.x;
    int ql = r * 256 + t;
    int v = ((t >> 4) * 160) + ((t & 15) * 16) + ((r >> 4) * 2560) + (r & 15);

    int cls = target[b * HW + v];

    const float* pS = PredS + b * 4 * HW + v;
    float a0 = pS[0], a1 = pS[HW], a2 = pS[2 * HW], a3 = pS[3 * HW];
    float mS = fmaxf(fmaxf(a0, a1), fmaxf(a2, a3));
    float e0 = expf(a0 - mS), e1 = expf(a1 - mS), e2 = expf(a2 - mS), e3 = expf(a3 - mS);
    float invS = 1.0f / (e0 + e1 + e2 + e3);
    float wei_s = ((cls == 0) ? e0 : (cls == 1) ? e1 : (cls == 2) ? e2 : e3) * invS;

    const float* pT = PredT + b * 4 * HW + v;
    float c0 = pT[0], c1 = pT[HW], c2 = pT[2 * HW], c3 = pT[3 * HW];
    float mT = fmaxf(fmaxf(c0, c1), fmaxf(c2, c3));
    float f0 = expf(c0 - mT), f1 = expf(c1 - mT), f2 = expf(c2 - mT), f3 = expf(c3 - mT);
    float invT = 1.0f / (f0 + f1 + f2 + f3);
    float tn0 = f0 * invT, tn1 = f1 * invT, tn2 = f2 * invT, tn3 = f3 * invT;
    float wei_t = (cls == 0) ? tn0 : (cls == 1) ? tn1 : (cls == 2) ? tn2 : tn3;

    cls_arr[b * HW + ql] = cls;
    wT_arr[b * HW + ql] = wei_t;
    w_arr[b * HW + ql] = (1.0f - wei_s) * wei_t;

    int ob = blk * 20;
#define RED1(expr, slot) { float rv = blockReduce256((expr), s4); if (t == 0) partial_prep[ob + (slot)] = rv; }
    RED1((cls == 0) ? 1.f : 0.f, 0)
    RED1((cls == 1) ? 1.f : 0.f, 1)
    RED1((cls == 2) ? 1.f : 0.f, 2)
    RED1((cls == 3) ? 1.f : 0.f, 3)
    RED1((cls == 0) ? tn0 : 0.f, 4)
    RED1((cls == 0) ? tn1 : 0.f, 5)
    RED1((cls == 0) ? tn2 : 0.f, 6)
    RED1((cls == 0) ? tn3 : 0.f, 7)
    RED1((cls == 1) ? tn0 : 0.f, 8)
    RED1((cls == 1) ? tn1 : 0.f, 9)
    RED1((cls == 1) ? tn2 : 0.f, 10)
    RED1((cls == 1) ? tn3 : 0.f, 11)
    RED1((cls == 2) ? tn0 : 0.f, 12)
    RED1((cls == 2) ? tn1 : 0.f, 13)
    RED1((cls == 2) ? tn2 : 0.f, 14)
    RED1((cls == 2) ? tn3 : 0.f, 15)
    RED1((cls == 3) ? tn0 : 0.f, 16)
    RED1((cls == 3) ? tn1 : 0.f, 17)
    RED1((cls == 3) ? tn2 : 0.f, 18)
    RED1((cls == 3) ? tn3 : 0.f, 19)
#undef RED1
}

// ---------- K1.5 (unchanged) ----------
__global__ void k15_red(const float* __restrict__ partial_prep,
                        float* __restrict__ cnt, float* __restrict__ E)
{
    int t = threadIdx.x;
    if (t < 80) {
        int b = t / 20, s = t - (t / 20) * 20;
        float a = 0.f;
        for (int r = 0; r < 100; ++r) a += partial_prep[(b * 100 + r) * 20 + s];
        if (s < 4) cnt[b * 4 + s] = a;
        else       E[b * 16 + (s - 4)] = a;
    }
}

// ---------- K2: W matrices in flat-q order (unchanged) ----------
__global__ __launch_bounds__(128) void k2_w(
    const float* __restrict__ Satt, const float* __restrict__ Tatt,
    const int* __restrict__ cls_arr, const float* __restrict__ wT_arr,
    float* __restrict__ W_S, float* __restrict__ W_T)
{
    __shared__ float Al[100 * 101];
    __shared__ int cls_s[100];
    __shared__ float wTs[100];
    int blk = blockIdx.x;
    int b = blk >> 8, i = blk & 255;
    int t = threadIdx.x;
    if (t < 100) {
        cls_s[t] = cls_arr[b * HW + i * 100 + t];
        wTs[t] = wT_arr[b * HW + i * 100 + t];
    }
    for (int f = t; f < 10000; f += 128) Al[f + f / 100] = Satt[b * 10000 + f];
    __syncthreads();
    if (t < 100) {
        float a0 = 0, a1 = 0, a2 = 0, a3 = 0;
        for (int jc = 0; jc < 100; ++jc) {
            float a = Al[t * 101 + jc];
            int cc = cls_s[jc];
            a0 += (cc == 0) ? a : 0.f;
            a1 += (cc == 1) ? a : 0.f;
            a2 += (cc == 2) ? a : 0.f;
            a3 += (cc == 3) ? a : 0.f;
        }
        int basew = b * 102400 + i * 100 + t;
        W_S[basew] = a0; W_S[basew + 25600] = a1; W_S[basew + 51200] = a2; W_S[basew + 76800] = a3;
    }
    __syncthreads();
    for (int f = t; f < 10000; f += 128) Al[f + f / 100] = Tatt[b * 10000 + f];
    __syncthreads();
    if (t < 100) {
        float a0 = 0, a1 = 0, a2 = 0, a3 = 0;
        for (int jc = 0; jc < 100; ++jc) {
            float a = Al[t * 101 + jc] * wTs[jc];
            int cc = cls_s[jc];
            a0 += (cc == 0) ? a : 0.f;
            a1 += (cc == 1) ? a : 0.f;
            a2 += (cc == 2) ? a : 0.f;
            a3 += (cc == 3) ? a : 0.f;
        }
        int basew = b * 102400 + i * 100 + t;
        W_T[basew] = a0; W_T[basew + 25600] = a1; W_T[basew + 51200] = a2; W_T[basew + 76800] = a3;
    }
}

// ---------- K3: permute feat -> bf16 featP (p-linear) + Sum reduction ----------
// grid 1024 = (b = x&3, c = x>>2), block 256.
__global__ __launch_bounds__(256) void k3_scan(
    const float* __restrict__ feat, const float* __restrict__ W,
    unsigned short* __restrict__ featP, float* __restrict__ SumOut)
{
    __shared__ float s4[4];
    int x = blockIdx.x;
    int b = x & 3, c = x >> 2;
    int t = threadIdx.x;
    const float* f = feat + (size_t)(b * 256 + c) * HW;
    const float* Wb = W + (size_t)b * 4 * HW;
    unsigned short* fp = featP + (size_t)(b * 256 + c) * HW;
    float as0 = 0, as1 = 0, as2 = 0, as3 = 0;

#define K3_BODY(NQ4)                                                         \
    {                                                                        \
        float fv[NQ4 * 4];                                                   \
        _Pragma("unroll")                                                    \
        for (int qq = 0; qq < NQ4; ++qq) {                                   \
            float4 a = *(const float4*)(f + vb + qq * 4);                    \
            fv[qq * 4] = a.x; fv[qq * 4 + 1] = a.y;                          \
            fv[qq * 4 + 2] = a.z; fv[qq * 4 + 3] = a.w;                      \
        }                                                                    \
        _Pragma("unroll")                                                    \
        for (int q = 0; q < NQ4 * 4; ++q) {                                  \
            int p = pbase + q * 256;                                         \
            float v = fv[q];                                                 \
            as0 += v * Wb[p];                                                \
            as1 += v * Wb[HW + p];                                           \
            as2 += v * Wb[2 * HW + p];                                       \
            as3 += v * Wb[3 * HW + p];                                       \
            fp[p] = f2bf(v);                                                 \
        }                                                                    \
    }

#pragma unroll 1
    for (int itg = 0; itg < 6; ++itg) {
        int vb = itg * 2560 + (t >> 4) * 160 + (t & 15) * 16;
        int pbase = itg * 4096 + t;
        K3_BODY(4)
    }
    {
        int itg = 6;
        int vb = itg * 2560 + (t >> 4) * 160 + (t & 15) * 16;
        int pbase = itg * 4096 + t;
        K3_BODY(1)
    }
#undef K3_BODY

    float r0 = blockReduce256(as0, s4);
    float r1 = blockReduce256(as1, s4);
    float r2 = blockReduce256(as2, s4);
    float r3 = blockReduce256(as3, s4);
    if (t == 0) {
        int o = (b * 256 + c) * 4;
        SumOut[o] = r0; SumOut[o + 1] = r1; SumOut[o + 2] = r2; SumOut[o + 3] = r3;
    }
}

// ---------- K4: MFMA einsum + fused n2/dot epilogue ----------
// grid 512: chalf = x&1, b = (x>>1)&3, g = x>>3 (4 i0 per block, one per wave)
__global__ __launch_bounds__(256, 2) void k4_mfma(
    const unsigned short* __restrict__ featP,
    const float* __restrict__ Att,
    const float* __restrict__ Sum,
    float* __restrict__ n2h, float* __restrict__ doth)
{
    __shared__ __align__(16) unsigned short featL[32 * 408 + 16]; // odd-16B row stride
    __shared__ __align__(16) unsigned short attL[100 * 136];      // [j][k], k padded 136

    int x = blockIdx.x;
    int chalf = x & 1, b = (x >> 1) & 3, g = x >> 3;
    int t = threadIdx.x, w = t >> 6, l = t & 63;

    // zero attL fully + featL pad regions (avoid NaN-bits x 0 in MFMA)
    for (int f = t; f < 13600; f += 256) attL[f] = 0;
    featL[(t >> 3) * 408 + 400 + (t & 7)] = 0;
    if (t < 16) featL[32 * 408 + t] = 0;
    __syncthreads();
    // fill attL[j][k] = Att[k][j] (bf16), k<100, j<100
    for (int f = t; f < 10000; f += 256) {
        int k = f / 100, j = f - k * 100;
        attL[j * 136 + k] = f2bf(Att[b * 10000 + f]);
    }

    float n2a[4] = {0, 0, 0, 0};
    float dota[4][4] = {};

    int lj = l & 31, lh = l >> 5;
    const unsigned short* brow0 = attL + (0 * 32 + lj) * 136 + lh * 8;
    const unsigned short* brow1 = attL + (1 * 32 + lj) * 136 + lh * 8;
    const unsigned short* brow2 = attL + (2 * 32 + lj) * 136 + lh * 8;
    int j3 = 96 + lj; if (j3 > 99) j3 = 99;
    const unsigned short* brow3 = attL + j3 * 136 + lh * 8;
    const unsigned short* arow = featL + lj * 408 + w * 100 + lh * 8;

#pragma unroll 1
    for (int ch = 0; ch < 4; ++ch) {
        __syncthreads();
        // stage 32 rows x 400 bf16 (linear reads from featP)
        {
            const unsigned short* src = featP + (size_t)(b * 256 + chalf * 128 + ch * 32 + (t >> 3)) * HW
                                        + g * 400 + (t & 7) * 8;
            unsigned short* dst = featL + (t >> 3) * 408 + (t & 7) * 8;
#pragma unroll
            for (int i = 0; i < 7; ++i) {
                int cb = (t & 7) + i * 8;
                if (cb < 50)
                    *(int4*)(dst + i * 64) = *(const int4*)(src + i * 64);
            }
        }
        __syncthreads();

        f32x16 acc0 = zero16(), acc1 = zero16(), acc2 = zero16(), acc3 = zero16();
#pragma unroll
        for (int ks = 0; ks < 7; ++ks) {
            ABu aF;
            aF.u[0] = *(const uint2*)(arow + ks * 16);
            aF.u[1] = *(const uint2*)(arow + ks * 16 + 4);
            bf16x8 b0 = *(const bf16x8*)(brow0 + ks * 16);
            acc0 = __builtin_amdgcn_mfma_f32_32x32x16_bf16(aF.v, b0, acc0, 0, 0, 0);
            bf16x8 b1 = *(const bf16x8*)(brow1 + ks * 16);
            acc1 = __builtin_amdgcn_mfma_f32_32x32x16_bf16(aF.v, b1, acc1, 0, 0, 0);
            bf16x8 b2 = *(const bf16x8*)(brow2 + ks * 16);
            acc2 = __builtin_amdgcn_mfma_f32_32x32x16_bf16(aF.v, b2, acc2, 0, 0, 0);
            bf16x8 b3 = *(const bf16x8*)(brow3 + ks * 16);
            acc3 = __builtin_amdgcn_mfma_f32_32x32x16_bf16(aF.v, b3, acc3, 0, 0, 0);
        }

        // epilogue: n2 += TS^2 ; dot[m] += TS * Sum[c][m]
        int cb0 = chalf * 128 + ch * 32 + (lh << 2);
#pragma unroll
        for (int r = 0; r < 16; ++r) {
            int cl = (r & 3) + ((r >> 2) << 3);
            float4 sv = *(const float4*)(Sum + (size_t)(b * 256 + cb0 + cl) * 4);
            float v;
            v = acc0[r]; n2a[0] += v * v;
            dota[0][0] += v * sv.x; dota[0][1] += v * sv.y; dota[0][2] += v * sv.z; dota[0][3] += v * sv.w;
            v = acc1[r]; n2a[1] += v * v;
            dota[1][0] += v * sv.x; dota[1][1] += v * sv.y; dota[1][2] += v * sv.z; dota[1][3] += v * sv.w;
            v = acc2[r]; n2a[2] += v * v;
            dota[2][0] += v * sv.x; dota[2][1] += v * sv.y; dota[2][2] += v * sv.z; dota[2][3] += v * sv.w;
            v = acc3[r]; n2a[3] += v * v;
            dota[3][0] += v * sv.x; dota[3][1] += v * sv.y; dota[3][2] += v * sv.z; dota[3][3] += v * sv.w;
        }
    }

    // combine lane halves (rows c and c+4 live in l and l+32)
#pragma unroll
    for (int nt = 0; nt < 4; ++nt) {
        n2a[nt] += __shfl_down(n2a[nt], 32, 64);
#pragma unroll
        for (int m = 0; m < 4; ++m) dota[nt][m] += __shfl_down(dota[nt][m], 32, 64);
    }
    if (l < 32) {
        int i0 = g * 4 + w;
        int pqb = b * HW + i0 * 100;
#pragma unroll
        for (int nt = 0; nt < 4; ++nt) {
            int j = nt * 32 + l;
            if (j < 100) {
                n2h[chalf * 102400 + pqb + j] = n2a[nt];
                float4 dv = {dota[nt][0], dota[nt][1], dota[nt][2], dota[nt][3]};
                *(float4*)(doth + chalf * 409600 + (size_t)(pqb + j) * 4) = dv;
            }
        }
    }
}

// ---------- K4.5: per-batch tables (unchanged) ----------
__global__ void k45_tbl(const float* __restrict__ SumTS, const float* __restrict__ SumTT,
                        const float* __restrict__ cnt, const float* __restrict__ E,
                        float* __restrict__ tbl)
{
    int t = threadIdx.x;
    if (t < 32) {
        int b = t >> 3, sj = t & 7, stv = sj >> 2, j = sj & 3;
        const float* S = stv ? SumTT : SumTS;
        float s = 0.f;
        for (int c = 0; c < 256; ++c) {
            float x = S[(b * 256 + c) * 4 + j];
            s += x * x;
        }
        tbl[b * 32 + stv * 4 + j] = sqrtf(s);
    } else if (t < 48) {
        int q = t - 32;
        int b = q >> 2, i = q & 3;
        tbl[b * 32 + 8 + 0 * 4 + i] = cnt[b * 4 + i] + 1e-6f;
        tbl[b * 32 + 8 + 1 * 4 + i] = cnt[b * 4 + (i ^ 2)] + 1e-6f;
        tbl[b * 32 + 8 + 2 * 4 + i] = cnt[b * 4 + (i ^ 3)] + 1.0f;
        tbl[b * 32 + 20 + 0 * 4 + i] = E[b * 16 + i * 4 + (i ^ 1)] + 1e-6f;
        tbl[b * 32 + 20 + 1 * 4 + i] = E[b * 16 + 5 * (i ^ 2)] + 1e-6f;
        tbl[b * 32 + 20 + 2 * 4 + i] = E[b * 16 + 5 * (i ^ 3)] + 1.0f;
    }
}

// ---------- K5: cosines + squared diff (reads half-pair partials) ----------
__global__ __launch_bounds__(256) void k5_final(
    const int* __restrict__ cls_arr, const float* __restrict__ w_arr,
    const float* __restrict__ n2S, const float* __restrict__ n2T,
    const float* __restrict__ dotS, const float* __restrict__ dotT,
    const float* __restrict__ tbl, double* __restrict__ partial_res)
{
    __shared__ double s4[4];
    int blk = blockIdx.x;
    int b = blk / 100, r = blk - b * 100;
    int t = threadIdx.x;
    int pq = b * HW + r * 256 + t;

    int i = cls_arr[pq];
    float wv = w_arr[pq];
    float sqS = sqrtf(n2S[pq] + n2S[102400 + pq]);
    float sqT = sqrtf(n2T[pq] + n2T[102400 + pq]);
    float4 dSa = *(const float4*)(dotS + (size_t)pq * 4);
    float4 dSb = *(const float4*)(dotS + 409600 + (size_t)pq * 4);
    float4 dTa = *(const float4*)(dotT + (size_t)pq * 4);
    float4 dTb = *(const float4*)(dotT + 409600 + (size_t)pq * 4);
    float4 dS = {dSa.x + dSb.x, dSa.y + dSb.y, dSa.z + dSb.z, dSa.w + dSb.w};
    float4 dT = {dTa.x + dTb.x, dTa.y + dTb.y, dTa.z + dTb.z, dTa.w + dTb.w};
    const float* tb = tbl + b * 32;

    double acc = 0.0;
#pragma unroll
    for (int v = 0; v < 3; ++v) {
        int j = i ^ (v + 1);
        float dsj = (j == 0) ? dS.x : (j == 1) ? dS.y : (j == 2) ? dS.z : dS.w;
        float dtj = (j == 0) ? dT.x : (j == 1) ? dT.y : (j == 2) ? dT.z : dT.w;
        float cnS = tb[j], cnT = tb[4 + j];
        float denS = tb[8 + v * 4 + i], denT = tb[20 + v * 4 + i];
        float cs = (dsj / denS) / fmaxf(sqS * (cnS / denS), 1e-8f);
        float ct = (dtj / denT) / fmaxf(sqT * (cnT / denT), 1e-8f);
        float vs = wv * cs, vt = wv * ct;
        float d = vs - vt;
        acc += (double)d * (double)d;
    }
    double tot = blockReduce256D(acc, s4);
    if (t == 0) partial_res[blk] = tot;
}

// ---------- K6 (unchanged) ----------
__global__ void k6_out(const double* __restrict__ partial_res, float* __restrict__ out)
{
    if (threadIdx.x == 0 && blockIdx.x == 0) {
        double s = 0.0;
        for (int q = 0; q < 400; ++q) s += partial_res[q];
        out[0] = (float)(s / 307200.0);
    }
}

// ---------- launch ----------
extern "C" void kernel_launch(void* const* d_in, const int* in_sizes, int n_in,
                              void* d_out, int out_size, void* d_ws, size_t ws_size,
                              hipStream_t stream)
{
    const float* feat_S  = (const float*)d_in[0];
    const float* feat_T  = (const float*)d_in[1];
    const float* Pred_S  = (const float*)d_in[2];
    const float* Pred_T  = (const float*)d_in[3];
    const float* S_atten = (const float*)d_in[4];
    const float* T_atten = (const float*)d_in[5];
    const int*   target  = (const int*)d_in[6];

    float* ws = (float*)d_ws;
    unsigned short* featP = (unsigned short*)d_ws;   // 26,214,400 shorts = 13,107,200 f32
    float* W_S   = ws + 13107200;            // 409600
    float* W_T   = ws + 13516800;            // 409600
    int*   cls_a = (int*)(ws + 13926400);    // 102400
    float* wT_a  = ws + 14028800;            // 102400
    float* w_a   = ws + 14131200;            // 102400
    float* SumTS = ws + 14233600;            // 4096
    float* SumTT = ws + 14237696;            // 4096
    float* n2S   = ws + 14241792;            // 204800 (2 halves)
    float* n2T   = ws + 14446592;            // 204800
    float* dotS  = ws + 14651392;            // 819200 (2 halves)
    float* dotT  = ws + 15470592;            // 819200
    float* pprep = ws + 16289792;            // 8000
    float* cnt   = ws + 16297792;            // 16
    float* E     = ws + 16297808;            // 64
    float* tbl   = ws + 16297872;            // 128
    double* pres = (double*)(ws + 16298000); // 400 doubles

    k1_prep<<<400, 256, 0, stream>>>(Pred_S, Pred_T, target, cls_a, wT_a, w_a, pprep);
    k15_red<<<1, 128, 0, stream>>>(pprep, cnt, E);
    k2_w<<<1024, 128, 0, stream>>>(S_atten, T_atten, cls_a, wT_a, W_S, W_T);

    // S side
    k3_scan<<<1024, 256, 0, stream>>>(feat_S, W_S, featP, SumTS);
    k4_mfma<<<512, 256, 0, stream>>>(featP, S_atten, SumTS, n2S, dotS);
    // T side (reuses featP buffer)
    k3_scan<<<1024, 256, 0, stream>>>(feat_T, W_T, featP, SumTT);
    k4_mfma<<<512, 256, 0, stream>>>(featP, T_atten, SumTT, n2T, dotT);

    k45_tbl<<<1, 64, 0, stream>>>(SumTS, SumTT, cnt, E, tbl);
    k5_final<<<400, 256, 0, stream>>>(cls_a, w_a, n2S, n2T, dotS, dotT, tbl, pres);
    k6_out<<<1, 64, 0, stream>>>(pres, (float*)d_out);
}